// Round 7
// baseline (29.332 us; speedup 1.0000x reference)
//
#include <hip/hip_runtime.h>
#include <hip/hip_fp16.h>

// Correlation layer, specialized: s1=2, s2=1, d=4 -> integer even sampling,
// bilinear weights exactly 0 -> pure gather:
// out[b, j*9+i, h1, w1] = (1/256) * sum_c x1[b,c,2h1,2w1] * x2[b,c,2(h1+j-4),2(w1+i-4)]
// (zero when displaced downsampled position is outside the 24x24 grid)

constexpr int NB = 16, NC = 256, NH = 48, NW = 48;
constexpr int H1 = 24, W1 = 24, NK = 81, HW = NH * NW;
constexpr int CSPLIT = 16, CPB = 16, CCH = 8;  // 16 blocks x 16ch, staged 8/chunk
constexpr int TH = 4;                           // h1 rows per block -> h1t 0..5
constexpr int NTILE = (H1 / TH) * NB;           // 96 spatial tiles
constexpr int NT = 216;                         // compute threads (4h x 9j x 6wg)
constexpr int PPT = 9 * NT;                     // 1944 Half4 per (tile,cz)
constexpr int OUTSZ = NB * NK * H1 * W1;        // 746496

struct alignas(8)  Half4 { __half2 a, b; };
struct alignas(16) Half8 { __half2 h[4]; };

// MODE 0: fp16 transposed partials in ws + coalesced reduce kernel
// MODE 1: atomicAdd fallback if ws too small
template<int MODE>
__global__ __launch_bounds__(256, 4) void corr_main(
    const float* __restrict__ x1, const float* __restrict__ x2,
    void* __restrict__ dst)
{
  const int t   = threadIdx.x;
  const int h1t = blockIdx.x;   // 0..5
  const int b   = blockIdx.y;   // 0..15
  const int cz  = blockIdx.z;   // 0..15
  const int h1base = h1t * TH;

  __shared__ float s1[CCH][TH][24];   // 3 KB
  __shared__ float s2[CCH][12][36];   // 13.8 KB (32 data cols + pad)

  const int h1l = t / 54;             // compute decomposition: 216 active
  const int rr  = t % 54;
  const int j   = rr / 6;
  const int wg  = rr % 6;

  const float* base1 = x1 + (size_t)(b * NC + cz * CPB) * HW;
  const float* base2 = x2 + (size_t)(b * NC + cz * CPB) * HW;

  float4 R2[6], R1[2];                // staging registers, reused across chunks

  auto loads = [&](int chunk) {
    const float* p2 = base2 + (size_t)chunk * CCH * HW;
    #pragma unroll
    for (int q = 0; q < 6; ++q) {
      const int idx = t + q * 256;    // xh(16) r(12) c(8) = 1536
      const int xh = idx & 15;
      const int r  = (idx >> 4) % 12;
      const int c  = idx / 192;
      const int ys = h1base - 4 + r;
      R2[q] = make_float4(0.f, 0.f, 0.f, 0.f);
      if (ys >= 0 && ys < H1 && xh >= 2 && xh <= 13)
        R2[q] = *(const float4*)&p2[(size_t)c * HW + (size_t)(2 * ys) * NW + (4 * xh - 8)];
    }
    const float* p1 = base1 + (size_t)chunk * CCH * HW;
    #pragma unroll
    for (int q = 0; q < 2; ++q) {
      const int idx = t + q * 256;    // xq(12) hh(4) c(8) = 384
      if (idx < 384) {
        const int xq = idx % 12;
        const int hh = (idx / 12) & 3;
        const int c  = idx / 48;
        R1[q] = *(const float4*)&p1[(size_t)c * HW + (size_t)(2 * (h1base + hh)) * NW + 4 * xq];
      }
    }
  };
  auto ldswrite = [&]() {             // keep .x,.z of each stride-2 float4
    #pragma unroll
    for (int q = 0; q < 6; ++q) {
      const int idx = t + q * 256;
      const int xh = idx & 15;
      const int r  = (idx >> 4) % 12;
      const int c  = idx / 192;
      *(float2*)&s2[c][r][2 * xh] = make_float2(R2[q].x, R2[q].z);
    }
    #pragma unroll
    for (int q = 0; q < 2; ++q) {
      const int idx = t + q * 256;
      if (idx < 384) {
        const int xq = idx % 12;
        const int hh = (idx / 12) & 3;
        const int c  = idx / 48;
        *(float2*)&s1[c][hh][2 * xq] = make_float2(R1[q].x, R1[q].z);
      }
    }
  };

  float acc[9][4];
  #pragma unroll
  for (int i = 0; i < 9; ++i) { acc[i][0]=0.f; acc[i][1]=0.f; acc[i][2]=0.f; acc[i][3]=0.f; }

  auto compute = [&]() {
    if (t >= NT) return;
    #pragma unroll
    for (int c = 0; c < CCH; ++c) {
      const float4 a4 = *(const float4*)&s1[c][h1l][wg * 4];
      const float* xr = &s2[c][h1l + j][wg * 4];
      const float4 b0 = *(const float4*)&xr[0];
      const float4 b1 = *(const float4*)&xr[4];
      const float4 b2 = *(const float4*)&xr[8];
      const float av[4]  = {a4.x, a4.y, a4.z, a4.w};
      const float xw[12] = {b0.x, b0.y, b0.z, b0.w, b1.x, b1.y, b1.z, b1.w,
                            b2.x, b2.y, b2.z, b2.w};
      #pragma unroll
      for (int i = 0; i < 9; ++i)
        #pragma unroll
        for (int w = 0; w < 4; ++w)
          acc[i][w] = fmaf(av[w], xw[w + i], acc[i][w]);
    }
  };

  // pipelined 2-chunk schedule: chunk-1 loads issue before chunk-0 compute
  loads(0);
  ldswrite();
  __syncthreads();
  loads(1);          // HBM latency hides under compute below
  compute();
  __syncthreads();   // all chunk-0 readers done before overwrite
  ldswrite();
  __syncthreads();
  compute();

  if (t >= NT) return;
  if (MODE == 0) {
    // transposed fp16 partials: wave store = 512 B contiguous per i
    const int tile = h1t * NB + b;
    Half4* pb = (Half4*)dst + ((size_t)cz * NTILE + tile) * PPT;
    #pragma unroll
    for (int i = 0; i < 9; ++i) {
      Half4 h;
      h.a = __floats2half2_rn(acc[i][0], acc[i][1]);
      h.b = __floats2half2_rn(acc[i][2], acc[i][3]);
      pb[i * NT + t] = h;
    }
  } else {
    float* out = (float*)dst;
    const int h1 = h1base + h1l;
    const int w1 = wg * 4;
    #pragma unroll
    for (int i = 0; i < 9; ++i) {
      const int k = j * 9 + i;
      #pragma unroll
      for (int w = 0; w < 4; ++w)
        atomicAdd(&out[((size_t)(b * NK + k) * H1 + h1) * W1 + w1 + w],
                  acc[i][w] * (1.f / 256.f));
    }
  }
}

// Coalesced reduce: each thread sums one Half8 (two adjacent Half4s) over 16
// cz slices -> two contiguous float4 output stores (32B).
__global__ __launch_bounds__(256) void corr_reduce(const Half4* __restrict__ part,
                                                   float* __restrict__ out)
{
  const int p = blockIdx.x * 256 + threadIdx.x;   // pair id, 0 .. 93311
  if (p >= OUTSZ / 8) return;
  const int tile = p / (PPT / 2);      // h1t*16 + b
  const int remp = p % (PPT / 2);
  const int rem  = remp * 2;           // Half4 index within slice (even)
  const int i    = rem / NT;
  const int tp   = rem % NT;           // even -> wg in {0,2,4}

  float s[8];
  #pragma unroll
  for (int w = 0; w < 8; ++w) s[w] = 0.f;
  #pragma unroll
  for (int cz = 0; cz < CSPLIT; ++cz) {
    const Half8 v = *(const Half8*)&part[((size_t)cz * NTILE + tile) * PPT + rem];
    #pragma unroll
    for (int q = 0; q < 4; ++q) {
      const float2 f = __half22float2(v.h[q]);
      s[2 * q]     += f.x;
      s[2 * q + 1] += f.y;
    }
  }
  const float sc = 1.f / (float)NC;
  const int b   = tile % NB;
  const int h1t = tile / NB;
  const int h1l = tp / 54;
  const int r2  = tp % 54;
  const int j   = r2 / 6;
  const int wg  = r2 % 6;
  const int k   = j * 9 + i;
  const int h1  = h1t * TH + h1l;
  float* o = &out[(((size_t)b * NK + k) * H1 + h1) * W1 + wg * 4];
  *(float4*)&o[0] = make_float4(s[0] * sc, s[1] * sc, s[2] * sc, s[3] * sc);
  *(float4*)&o[4] = make_float4(s[4] * sc, s[5] * sc, s[6] * sc, s[7] * sc);
}

extern "C" void kernel_launch(void* const* d_in, const int* in_sizes, int n_in,
                              void* d_out, int out_size, void* d_ws, size_t ws_size,
                              hipStream_t stream) {
  const float* x1 = (const float*)d_in[0];
  const float* x2 = (const float*)d_in[1];
  float* out = (float*)d_out;

  const size_t need = (size_t)CSPLIT * NTILE * PPT * sizeof(Half4);  // ~23.9 MB
  const dim3 grid(H1 / TH, NB, CSPLIT);   // (6, 16, 16) = 1536 blocks
  if (ws_size >= need) {
    corr_main<0><<<grid, 256, 0, stream>>>(x1, x2, d_ws);
    corr_reduce<<<(OUTSZ / 8 + 255) / 256, 256, 0, stream>>>((const Half4*)d_ws, out);
  } else {
    hipMemsetAsync(d_out, 0, (size_t)OUTSZ * sizeof(float), stream);
    corr_main<1><<<grid, 256, 0, stream>>>(x1, x2, d_out);
  }
}